// Round 6
// baseline (503.263 us; speedup 1.0000x reference)
//
#include <hip/hip_runtime.h>
#include <hip/hip_fp16.h>
#include <cmath>

// B=2, H=8, S=4096, d=64; fp32 in/out.
// e = (Q@K)/sqrt(512); a = softmax over HEADS; o = a@V.
// Head-softmax => t separable (partials add). K pre-scaled by scale*log2e.
// ONE barrier per tile: producer writes exp2(e') f16 to EA; consumer (PV phase)
// computes Z = sum over heads itself from EA and normalizes in-register.
// NO inline asm: exp2f() only (R4/R5 failures attributed to v_exp_f32 inline asm
// consuming MFMA results without hazard handling).
#define S_LEN 4096
#define NHEAD 8
#define HEADD 64
#define BM 32
#define BN 32
#define TSPLIT 8
#define TCHUNK (S_LEN / TSPLIT)      // 512 keys per block
#define NTILE (TCHUNK / BN)          // 16 iterations
#define EAP 40                       // u16 pitch, 80 B rows: u16 score writes 2-way, b128 reads uniform
#define KPRE 0.0637588696f           // (1/sqrt(512)) * log2(e)

#define KT_BYTES (2ull * NHEAD * S_LEN * HEADD * 2)       // 8,388,608 bf16 K^T [t][k]
#define VT_OFF   KT_BYTES
#define PART_OFF (2 * KT_BYTES)                            // 16,777,216
#define PART_U32 (16ull * NHEAD * 2048 * 64)               // 16,777,216 u32 (16 combos)
#define WS_FULL  (PART_OFF + PART_U32 * 4)                 // 83,886,080

typedef __attribute__((ext_vector_type(8))) short   short8;
typedef __attribute__((ext_vector_type(4))) float   float4v;

__device__ __forceinline__ unsigned short f2bf(float f) {  // fp32 -> bf16 RNE
  unsigned int u = __float_as_uint(f);
  u += 0x7FFFu + ((u >> 16) & 1u);
  return (unsigned short)(u >> 16);
}

// ---------------- pre-pass: K [b,h,64,4096] f32 -> Kt [b,h,4096,64] bf16 * KPRE
//                  V [b,h,4096,64] f32 -> Vt [b,h,64,4096] bf16
__global__ __launch_bounds__(256)
void prepass_cvt(const float* __restrict__ K, const float* __restrict__ V,
                 unsigned short* __restrict__ Kt, unsigned short* __restrict__ Vt) {
  __shared__ __align__(16) unsigned short lds[64][72];
  const int tid = threadIdx.x;
  const int isV = blockIdx.x >> 10;
  const int idx = blockIdx.x & 1023;
  const int bh  = idx >> 6;
  const int t0  = (idx & 63) << 6;
  if (!isV) {
    const float* in = K + (size_t)bh * HEADD * S_LEN;      // [k][t]
#pragma unroll
    for (int j = 0; j < 16; ++j) {
      int li = j * 256 + tid;
      int k = li >> 6, t = li & 63;
      lds[t][k] = f2bf(in[(size_t)k * S_LEN + t0 + t] * KPRE);
    }
    __syncthreads();
    unsigned short* out = Kt + (size_t)bh * S_LEN * HEADD; // [t][k]
    int t = tid >> 2, k0 = (tid & 3) << 4;
    *(short8*)(out + (size_t)(t0 + t) * HEADD + k0)     = *(const short8*)&lds[t][k0];
    *(short8*)(out + (size_t)(t0 + t) * HEADD + k0 + 8) = *(const short8*)&lds[t][k0 + 8];
  } else {
    const float* in = V + (size_t)bh * S_LEN * HEADD;      // [t][d]
#pragma unroll
    for (int j = 0; j < 16; ++j) {
      int li = j * 256 + tid;
      int t = li >> 6, d = li & 63;
      lds[d][t] = f2bf(in[(size_t)(t0 + t) * HEADD + d]);
    }
    __syncthreads();
    unsigned short* out = Vt + (size_t)bh * HEADD * S_LEN; // [d][t]
    int d = tid >> 2, c0 = (tid & 3) << 4;
    *(short8*)(out + (size_t)d * S_LEN + t0 + c0)     = *(const short8*)&lds[d][c0];
    *(short8*)(out + (size_t)d * S_LEN + t0 + c0 + 8) = *(const short8*)&lds[d][c0 + 8];
  }
}

// ---------------- main: 2048 blocks x 512 thr (8 waves, wave=head), BM=32 q-rows.
// One barrier/iter; EA ping-pong protects WAR across iterations.
__global__ __launch_bounds__(512, 6)
void attn_main(const float* __restrict__ Q, const unsigned short* __restrict__ Kt,
               const unsigned short* __restrict__ Vt, unsigned int* __restrict__ part) {
  __shared__ __align__(16) unsigned short EA[2][NHEAD][BM][EAP];  // 40,960 B

  const int tid  = threadIdx.x;
  const int h    = tid >> 6;
  const int lane = tid & 63;
  const int quad = lane >> 4;
  const int l15  = lane & 15;
  const int combo = blockIdx.x & 15;
  const int b  = combo & 1;
  const int tc = combo >> 1;
  const int s0 = (blockIdx.x >> 4) * BM;

  const float* Qg = Q + (size_t)(b * NHEAD + h) * S_LEN * HEADD;
  const unsigned short* Kth = Kt + (size_t)(b * NHEAD + h) * S_LEN * HEADD;  // [t][k]
  const unsigned short* Vth = Vt + (size_t)(b * NHEAD + h) * HEADD * S_LEN;  // [d][t]

  // Q fragments (A-layout 16x16x32: m=l15, k=quad*8+j)
  short8 qf[2][2];
#pragma unroll
  for (int ss = 0; ss < 2; ++ss)
#pragma unroll
    for (int kk = 0; kk < 2; ++kk) {
      const float* p = Qg + (size_t)(s0 + ss * 16 + l15) * HEADD + kk * 32 + quad * 8;
      float4v a0 = *(const float4v*)p;
      float4v a1 = *(const float4v*)(p + 4);
      short8 f;
      f[0] = (short)f2bf(a0[0]); f[1] = (short)f2bf(a0[1]);
      f[2] = (short)f2bf(a0[2]); f[3] = (short)f2bf(a0[3]);
      f[4] = (short)f2bf(a1[0]); f[5] = (short)f2bf(a1[1]);
      f[6] = (short)f2bf(a1[2]); f[7] = (short)f2bf(a1[3]);
      qf[ss][kk] = f;
    }

  float4v acc[2][4];
#pragma unroll
  for (int ss = 0; ss < 2; ++ss)
#pragma unroll
    for (int df = 0; df < 4; ++df)
      acc[ss][df] = (float4v){0.f, 0.f, 0.f, 0.f};

  const int tbase = tc * TCHUNK;

  for (int it = 0; it < NTILE; ++it) {
    const int t0 = tbase + it * BN;
    const int p  = it & 1;

    // ---- producer: QK^T, exp2 (compiler intrinsic path), f16 -> EA[p][h] ----
    {
      short8 kf[2][2];
#pragma unroll
      for (int ts = 0; ts < 2; ++ts)
#pragma unroll
        for (int kh = 0; kh < 2; ++kh)
          kf[ts][kh] = *(const short8*)(Kth + (size_t)(t0 + ts * 16 + l15) * HEADD + kh * 32 + quad * 8);
#pragma unroll
      for (int ss = 0; ss < 2; ++ss)
#pragma unroll
        for (int ts = 0; ts < 2; ++ts) {
          float4v e = (float4v){0.f, 0.f, 0.f, 0.f};
          e = __builtin_amdgcn_mfma_f32_16x16x32_bf16(qf[ss][0], kf[ts][0], e, 0, 0, 0);
          e = __builtin_amdgcn_mfma_f32_16x16x32_bf16(qf[ss][1], kf[ts][1], e, 0, 0, 0);
#pragma unroll
          for (int r = 0; r < 4; ++r) {  // C/D: col=l15 (t), row=quad*4+r (s)
            float ex = exp2f(e[r]);
            EA[p][h][ss * 16 + quad * 4 + r][ts * 16 + l15] =
                __half_as_ushort(__float2half(ex));
          }
        }
    }
    __syncthreads();  // the ONLY barrier per iteration

    // ---- consumer: vf loads first (independent of EA -> overlap L2 latency) ----
    short8 vf[4];
#pragma unroll
    for (int df = 0; df < 4; ++df)
      vf[df] = *(const short8*)(Vth + (size_t)(df * 16 + l15) * S_LEN + t0 + quad * 8);

    // ---- build normalized A-fragments (af) with in-register head-sum Z ----
    short8 af[2];
#pragma unroll
    for (int ss = 0; ss < 2; ++ss) {
      const int row = ss * 16 + l15;
      union { short8 s8; __half2 h2[4]; } w, own;
      __half2 z[4];
      w.s8 = *(const short8*)&EA[p][0][row][quad * 8];
      z[0] = w.h2[0]; z[1] = w.h2[1]; z[2] = w.h2[2]; z[3] = w.h2[3];
#pragma unroll
      for (int hh = 1; hh < 8; ++hh) {
        w.s8 = *(const short8*)&EA[p][hh][row][quad * 8];
        z[0] = __hadd2(z[0], w.h2[0]); z[1] = __hadd2(z[1], w.h2[1]);
        z[2] = __hadd2(z[2], w.h2[2]); z[3] = __hadd2(z[3], w.h2[3]);
      }
      own.s8 = *(const short8*)&EA[p][h][row][quad * 8];
      short8 a8;
#pragma unroll
      for (int j = 0; j < 4; ++j) {
        float il = __builtin_amdgcn_rcpf(__low2float(z[j]));
        float ih = __builtin_amdgcn_rcpf(__high2float(z[j]));
        a8[2 * j]     = (short)f2bf(__low2float(own.h2[j]) * il);
        a8[2 * j + 1] = (short)f2bf(__high2float(own.h2[j]) * ih);
      }
      af[ss] = a8;
    }

    // ---- PV ----
#pragma unroll
    for (int ss = 0; ss < 2; ++ss)
#pragma unroll
      for (int df = 0; df < 4; ++df)
        acc[ss][df] = __builtin_amdgcn_mfma_f32_16x16x32_bf16(af[ss], vf[df], acc[ss][df], 0, 0, 0);
    // no trailing barrier: next iteration's producer writes EA[p^1]
  }

  // ---- epilogue: partials as packed bf16 s-pairs. layout [tc][b][h][sp][d]
  unsigned int* pb = part + ((size_t)(tc * 2 + b) * NHEAD + h) * (2048ull * 64);
  const int spb = (s0 >> 1) + quad * 2;
#pragma unroll
  for (int ss = 0; ss < 2; ++ss)
#pragma unroll
    for (int df = 0; df < 4; ++df)
#pragma unroll
      for (int rp = 0; rp < 2; ++rp) {
        unsigned int ulo = __float_as_uint(acc[ss][df][rp * 2])     + 0x8000u;
        unsigned int uhi = __float_as_uint(acc[ss][df][rp * 2 + 1]) + 0x8000u;
        unsigned int pk  = __builtin_amdgcn_perm(uhi, ulo, 0x07060302u);
        pb[(size_t)(spb + ss * 8 + rp) * 64 + df * 16 + l15] = pk;
      }
}

// ---------------- reduce: sum 8 tc-partials (packed bf16 pairs) -> fp32 O ----------------
__global__ __launch_bounds__(256)
void reduce_partials(const unsigned int* __restrict__ part, float* __restrict__ out) {
  const size_t TCSTRIDE = 2097152;   // u32 per tc = 2b*8h*2048sp*64d
  size_t i = ((size_t)blockIdx.x * 256 + threadIdx.x) * 4;
  if (i >= TCSTRIDE) return;
  float lo[4] = {0.f, 0.f, 0.f, 0.f}, hi[4] = {0.f, 0.f, 0.f, 0.f};
#pragma unroll
  for (int tc = 0; tc < 8; ++tc) {
    uint4 v = *(const uint4*)(part + tc * TCSTRIDE + i);
    lo[0] += __uint_as_float(v.x << 16); hi[0] += __uint_as_float(v.x & 0xffff0000u);
    lo[1] += __uint_as_float(v.y << 16); hi[1] += __uint_as_float(v.y & 0xffff0000u);
    lo[2] += __uint_as_float(v.z << 16); hi[2] += __uint_as_float(v.z & 0xffff0000u);
    lo[3] += __uint_as_float(v.w << 16); hi[3] += __uint_as_float(v.w & 0xffff0000u);
  }
  size_t bh = i >> 17;                    // 131072 u32 per (b,h)
  unsigned int r = (unsigned int)(i & 131071u);
  unsigned int sp = r >> 6, d = r & 63u;
  float* o = out + ((size_t)bh * S_LEN + 2 * sp) * HEADD + d;
  *(float4v*)o        = (float4v){lo[0], lo[1], lo[2], lo[3]};
  *(float4v*)(o + 64) = (float4v){hi[0], hi[1], hi[2], hi[3]};
}

// ---------------- zero-workspace fallback (round-1 kernel, known correct) ----------------
__global__ __launch_bounds__(512, 2)
void attn_fallback(const float* __restrict__ Qg0, const float* __restrict__ Kg0,
                   const float* __restrict__ Vg0, float* __restrict__ Og0) {
  __shared__ __align__(16) unsigned short Klds[NHEAD][32][72];
  __shared__ __align__(16) unsigned short Vlds[NHEAD][HEADD][40];
  __shared__ __align__(16) unsigned short EA2[NHEAD][64][40];
  const int tid = threadIdx.x, h = tid >> 6, lane = tid & 63, quad = lane >> 4, l15 = lane & 15;
  const int b = blockIdx.x >> 6, s0 = (blockIdx.x & 63) * 64;
  const float* Qg = Qg0 + ((size_t)(b * NHEAD + h)) * S_LEN * HEADD;
  const float* Kg = Kg0 + ((size_t)(b * NHEAD + h)) * HEADD * S_LEN;
  const float* Vg = Vg0 + ((size_t)(b * NHEAD + h)) * S_LEN * HEADD;
  float* Og = Og0 + ((size_t)(b * NHEAD + h)) * S_LEN * HEADD;
  const float SC = 0.04419417382415922f;
  short8 qf[4][2];
#pragma unroll
  for (int ss = 0; ss < 4; ++ss)
#pragma unroll
    for (int kk = 0; kk < 2; ++kk) {
      const float* p = Qg + (size_t)(s0 + ss * 16 + l15) * HEADD + kk * 32 + quad * 8;
      float4v a0 = *(const float4v*)p; float4v a1 = *(const float4v*)(p + 4);
      short8 f;
      f[0] = (short)f2bf(a0[0]); f[1] = (short)f2bf(a0[1]); f[2] = (short)f2bf(a0[2]); f[3] = (short)f2bf(a0[3]);
      f[4] = (short)f2bf(a1[0]); f[5] = (short)f2bf(a1[1]); f[6] = (short)f2bf(a1[2]); f[7] = (short)f2bf(a1[3]);
      qf[ss][kk] = f;
    }
  float4v acc[4][4];
#pragma unroll
  for (int ss = 0; ss < 4; ++ss)
#pragma unroll
    for (int ds = 0; ds < 4; ++ds) acc[ss][ds] = (float4v){0.f, 0.f, 0.f, 0.f};
  const int koct = lane >> 3, kt4 = (lane & 7) * 4, vdq = lane & 15, vtg = lane >> 4;
  const int s_sm = tid >> 3, t4_sm = (tid & 7) * 4;
  for (int it = 0; it < S_LEN / 32; ++it) {
    const int t0 = it * 32;
    {
      float buf[8][4];
#pragma unroll
      for (int j = 0; j < 8; ++j) {
        float4v v = *(const float4v*)(Kg + (size_t)(koct * 8 + j) * S_LEN + t0 + kt4);
        buf[j][0] = v[0]; buf[j][1] = v[1]; buf[j][2] = v[2]; buf[j][3] = v[3];
      }
#pragma unroll
      for (int c = 0; c < 4; ++c) {
        short8 f;
#pragma unroll
        for (int j = 0; j < 8; ++j) f[j] = (short)f2bf(buf[j][c]);
        *(short8*)&Klds[h][kt4 + c][koct * 8] = f;
      }
    }
    {
      float buf[8][4];
#pragma unroll
      for (int j = 0; j < 8; ++j) {
        float4v v = *(const float4v*)(Vg + (size_t)(t0 + vtg * 8 + j) * HEADD + vdq * 4);
        buf[j][0] = v[0]; buf[j][1] = v[1]; buf[j][2] = v[2]; buf[j][3] = v[3];
      }
#pragma unroll
      for (int c = 0; c < 4; ++c) {
        short8 f;
#pragma unroll
        for (int j = 0; j < 8; ++j) f[j] = (short)f2bf(buf[j][c]);
        *(short8*)&Vlds[h][vdq * 4 + c][vtg * 8] = f;
      }
    }
    __syncthreads();
#pragma unroll
    for (int ts = 0; ts < 2; ++ts) {
      short8 kf0 = *(const short8*)&Klds[h][ts * 16 + l15][quad * 8];
      short8 kf1 = *(const short8*)&Klds[h][ts * 16 + l15][32 + quad * 8];
#pragma unroll
      for (int ss = 0; ss < 4; ++ss) {
        float4v e = (float4v){0.f, 0.f, 0.f, 0.f};
        e = __builtin_amdgcn_mfma_f32_16x16x32_bf16(qf[ss][0], kf0, e, 0, 0, 0);
        e = __builtin_amdgcn_mfma_f32_16x16x32_bf16(qf[ss][1], kf1, e, 0, 0, 0);
#pragma unroll
        for (int r = 0; r < 4; ++r)
          EA2[h][ss * 16 + quad * 4 + r][ts * 16 + l15] = __half_as_ushort(__float2half(e[r] * SC));
      }
    }
    __syncthreads();
    {
      float ev[8][4];
#pragma unroll
      for (int hh = 0; hh < 8; ++hh) {
        unsigned long long u = *(const unsigned long long*)&EA2[hh][s_sm][t4_sm];
        ev[hh][0] = __half2float(__ushort_as_half((unsigned short)u));
        ev[hh][1] = __half2float(__ushort_as_half((unsigned short)(u >> 16)));
        ev[hh][2] = __half2float(__ushort_as_half((unsigned short)(u >> 32)));
        ev[hh][3] = __half2float(__ushort_as_half((unsigned short)(u >> 48)));
      }
#pragma unroll
      for (int c = 0; c < 4; ++c) {
        float m = ev[0][c];
#pragma unroll
        for (int hh = 1; hh < 8; ++hh) m = fmaxf(m, ev[hh][c]);
        float sum = 0.f;
#pragma unroll
        for (int hh = 0; hh < 8; ++hh) { float x = __expf(ev[hh][c] - m); ev[hh][c] = x; sum += x; }
        float inv = __builtin_amdgcn_rcpf(sum);
#pragma unroll
        for (int hh = 0; hh < 8; ++hh) ev[hh][c] *= inv;
      }
#pragma unroll
      for (int hh = 0; hh < 8; ++hh) {
        unsigned short u0 = f2bf(ev[hh][0]), u1 = f2bf(ev[hh][1]), u2 = f2bf(ev[hh][2]), u3 = f2bf(ev[hh][3]);
        unsigned long long w = (unsigned long long)u0 | ((unsigned long long)u1 << 16) |
                               ((unsigned long long)u2 << 32) | ((unsigned long long)u3 << 48);
        *(unsigned long long*)&EA2[hh][s_sm][t4_sm] = w;
      }
    }
    __syncthreads();
    {
      short8 af[4], vf[4];
#pragma unroll
      for (int ss = 0; ss < 4; ++ss) af[ss] = *(const short8*)&EA2[h][ss * 16 + l15][quad * 8];
#pragma unroll
      for (int ds = 0; ds < 4; ++ds) vf[ds] = *(const short8*)&Vlds[h][ds * 16 + l15][quad * 8];
#pragma unroll
      for (int ss = 0; ss < 4; ++ss)
#pragma unroll
        for (int ds = 0; ds < 4; ++ds)
          acc[ss][ds] = __builtin_amdgcn_mfma_f32_16x16x32_bf16(af[ss], vf[ds], acc[ss][ds], 0, 0, 0);
    }
    __syncthreads();
  }
#pragma unroll
  for (int ss = 0; ss < 4; ++ss)
#pragma unroll
    for (int ds = 0; ds < 4; ++ds)
#pragma unroll
      for (int r = 0; r < 4; ++r)
        Og[(size_t)(s0 + ss * 16 + quad * 4 + r) * HEADD + ds * 16 + l15] = acc[ss][ds][r];
}

extern "C" void kernel_launch(void* const* d_in, const int* in_sizes, int n_in,
                              void* d_out, int out_size, void* d_ws, size_t ws_size,
                              hipStream_t stream) {
  const float* Q = (const float*)d_in[0];
  const float* K = (const float*)d_in[1];
  const float* V = (const float*)d_in[2];
  float* O = (float*)d_out;

  if (ws_size >= WS_FULL) {
    unsigned short* Kt = (unsigned short*)d_ws;
    unsigned short* Vt = (unsigned short*)((char*)d_ws + VT_OFF);
    unsigned int* part = (unsigned int*)((char*)d_ws + PART_OFF);
    hipLaunchKernelGGL(prepass_cvt, dim3(2048), dim3(256), 0, stream, K, V, Kt, Vt);
    hipLaunchKernelGGL(attn_main, dim3(2048), dim3(512), 0, stream, Q, Kt, Vt, part);
    hipLaunchKernelGGL(reduce_partials, dim3(2048), dim3(256), 0, stream, part, O);
  } else {
    hipLaunchKernelGGL(attn_fallback, dim3(128), dim3(512), 0, stream, Q, K, V, O);
  }
}

// Round 7
// 353.190 us; speedup vs baseline: 1.4249x; 1.4249x over previous
//
#include <hip/hip_runtime.h>
#include <hip/hip_fp16.h>
#include <cmath>

// B=2, H=8, S=4096, d=64; fp32 in/out.
// e = (Q@K)/sqrt(512); a = softmax over HEADS; o = a@V.
// Head-softmax => t separable (partials add). K pre-scaled by scale*log2e;
// softmax uses exp2f (NO inline asm -- R4/R5 failed on v_exp_f32 asm vs MFMA hazard).
// R7 = R3 two-barrier structure + EAP=40 (score writes 2-way, free) +
// XCD-pinned combos (blockIdx&7 -> each XCD holds 2 K/V slices = 2MB, L2-resident) +
// LDS-free vectorized prepass.
#define S_LEN 4096
#define NHEAD 8
#define HEADD 64
#define BM 32
#define BN 32
#define TSPLIT 8
#define TCHUNK (S_LEN / TSPLIT)      // 512 keys per block
#define NTILE (TCHUNK / BN)          // 16 iterations
#define EAP 40                       // u16 pitch; dword pitch 20: 80*quad%128=16*(quad&1) -> <=2-way
#define KPRE 0.0637588696f           // (1/sqrt(512)) * log2(e)

#define KT_BYTES (2ull * NHEAD * S_LEN * HEADD * 2)       // 8,388,608 bf16 K^T [t][k]
#define VT_OFF   KT_BYTES
#define PART_OFF (2 * KT_BYTES)                            // 16,777,216
#define PART_U32 (16ull * NHEAD * 2048 * 64)               // 16,777,216 u32 (16 combos)
#define WS_FULL  (PART_OFF + PART_U32 * 4)                 // 83,886,080

typedef __attribute__((ext_vector_type(8))) short   short8;
typedef __attribute__((ext_vector_type(4))) float   float4v;

__device__ __forceinline__ unsigned short f2bf(float f) {  // fp32 -> bf16 RNE
  unsigned int u = __float_as_uint(f);
  u += 0x7FFFu + ((u >> 16) & 1u);
  return (unsigned short)(u >> 16);
}

// ---------------- pre-pass v2: LDS-free, float4 reads, in-register 8x4 transpose,
// b128 global writes. 1024 blocks x 256 thr (512 K-blocks, 512 V-blocks).
// K [bh,64,4096] f32 -> Kt [bh,4096,64] bf16*KPRE ; V [bh,4096,64] f32 -> Vt [bh,64,4096] bf16
__global__ __launch_bounds__(256)
void prepass_cvt(const float* __restrict__ K, const float* __restrict__ V,
                 unsigned short* __restrict__ Kt, unsigned short* __restrict__ Vt) {
  const int tid  = threadIdx.x;
  const int wave = tid >> 6, lane = tid & 63;
  const int isV  = blockIdx.x >> 9;
  const int idx  = blockIdx.x & 511;
  const int bh   = idx >> 5;                       // 16 bh
  const int t0   = (idx & 31) * 128 + wave * 32;   // block covers 128 t; wave covers 32 t
  if (!isV) {
    const float* in = K + (size_t)bh * HEADD * S_LEN;       // [k][t]
    unsigned short* out = Kt + (size_t)bh * S_LEN * HEADD;  // [t][k]
    const int koct = lane >> 3;          // k = koct*8 + j
    const int kt4  = (lane & 7) * 4;     // 4 t per lane
    float buf[8][4];
#pragma unroll
    for (int j = 0; j < 8; ++j) {
      float4v v = *(const float4v*)(in + (size_t)(koct * 8 + j) * S_LEN + t0 + kt4);
      buf[j][0] = v[0]; buf[j][1] = v[1]; buf[j][2] = v[2]; buf[j][3] = v[3];
    }
#pragma unroll
    for (int c = 0; c < 4; ++c) {
      short8 f;
#pragma unroll
      for (int j = 0; j < 8; ++j) f[j] = (short)f2bf(buf[j][c] * KPRE);
      *(short8*)(out + (size_t)(t0 + kt4 + c) * HEADD + koct * 8) = f;
    }
  } else {
    const float* in = V + (size_t)bh * S_LEN * HEADD;       // [t][d]
    unsigned short* out = Vt + (size_t)bh * HEADD * S_LEN;  // [d][t]
    const int vdq = lane & 15;           // d = vdq*4 + c
    const int vtg = lane >> 4;           // t = t0 + vtg*8 + j
    float buf[8][4];
#pragma unroll
    for (int j = 0; j < 8; ++j) {
      float4v v = *(const float4v*)(in + (size_t)(t0 + vtg * 8 + j) * HEADD + vdq * 4);
      buf[j][0] = v[0]; buf[j][1] = v[1]; buf[j][2] = v[2]; buf[j][3] = v[3];
    }
#pragma unroll
    for (int c = 0; c < 4; ++c) {
      short8 f;
#pragma unroll
      for (int j = 0; j < 8; ++j) f[j] = (short)f2bf(buf[j][c]);
      *(short8*)(out + (size_t)(vdq * 4 + c) * S_LEN + t0 + vtg * 8) = f;
    }
  }
}

// ---------------- main: 2048 blocks x 512 thr (8 waves, wave=head), BM=32 q-rows.
// combo pinned to blockIdx&7 (+bit3): XCD x handles (b=x&1, tc in {x>>1, x>>1+4}).
__global__ __launch_bounds__(512, 6)
void attn_main(const float* __restrict__ Q, const unsigned short* __restrict__ Kt,
               const unsigned short* __restrict__ Vt, unsigned int* __restrict__ part) {
  __shared__ __align__(16) unsigned short EA[2][NHEAD][BM][EAP];  // 40,960 B

  const int tid  = threadIdx.x;
  const int h    = tid >> 6;
  const int lane = tid & 63;
  const int quad = lane >> 4;
  const int l15  = lane & 15;
  const int combo = (blockIdx.x & 7) | (((blockIdx.x >> 3) & 1) << 3);
  const int b  = combo & 1;
  const int tc = combo >> 1;
  const int s0 = (blockIdx.x >> 4) * BM;

  const float* Qg = Q + (size_t)(b * NHEAD + h) * S_LEN * HEADD;
  const unsigned short* Kth = Kt + (size_t)(b * NHEAD + h) * S_LEN * HEADD;  // [t][k]
  const unsigned short* Vth = Vt + (size_t)(b * NHEAD + h) * HEADD * S_LEN;  // [d][t]

  // Q fragments (A-layout 16x16x32: m=l15, k=quad*8+j)
  short8 qf[2][2];
#pragma unroll
  for (int ss = 0; ss < 2; ++ss)
#pragma unroll
    for (int kk = 0; kk < 2; ++kk) {
      const float* p = Qg + (size_t)(s0 + ss * 16 + l15) * HEADD + kk * 32 + quad * 8;
      float4v a0 = *(const float4v*)p;
      float4v a1 = *(const float4v*)(p + 4);
      short8 f;
      f[0] = (short)f2bf(a0[0]); f[1] = (short)f2bf(a0[1]);
      f[2] = (short)f2bf(a0[2]); f[3] = (short)f2bf(a0[3]);
      f[4] = (short)f2bf(a1[0]); f[5] = (short)f2bf(a1[1]);
      f[6] = (short)f2bf(a1[2]); f[7] = (short)f2bf(a1[3]);
      qf[ss][kk] = f;
    }

  float4v acc[2][4];
#pragma unroll
  for (int ss = 0; ss < 2; ++ss)
#pragma unroll
    for (int df = 0; df < 4; ++df)
      acc[ss][df] = (float4v){0.f, 0.f, 0.f, 0.f};

  const int s_sm = tid >> 4;        // 0..31
  const int tp   = tid & 15;        // t-pair index (t = 2*tp, 2*tp+1)

  const int tbase = tc * TCHUNK;

  for (int it = 0; it < NTILE; ++it) {
    const int t0 = tbase + it * BN;
    const int p  = it & 1;

    // ---- QK^T: kf direct from global bf16 [t][k]; raw log2-domain scores -> f16 in EA ----
    {
      short8 kf[2][2];
#pragma unroll
      for (int ts = 0; ts < 2; ++ts)
#pragma unroll
        for (int kh = 0; kh < 2; ++kh)
          kf[ts][kh] = *(const short8*)(Kth + (size_t)(t0 + ts * 16 + l15) * HEADD + kh * 32 + quad * 8);
#pragma unroll
      for (int ss = 0; ss < 2; ++ss)
#pragma unroll
        for (int ts = 0; ts < 2; ++ts) {
          float4v e = (float4v){0.f, 0.f, 0.f, 0.f};
          e = __builtin_amdgcn_mfma_f32_16x16x32_bf16(qf[ss][0], kf[ts][0], e, 0, 0, 0);
          e = __builtin_amdgcn_mfma_f32_16x16x32_bf16(qf[ss][1], kf[ts][1], e, 0, 0, 0);
#pragma unroll
          for (int r = 0; r < 4; ++r)   // C/D: col=l15 (t), row=quad*4+r (s)
            EA[p][h][ss * 16 + quad * 4 + r][ts * 16 + l15] =
                __half_as_ushort(__float2half(e[r]));
        }
    }
    __syncthreads();

    // ---- softmax over heads per (s,t): p_h = exp2(e'_h)/sum (exp2f intrinsic only) ----
    {
      unsigned int x[8];
#pragma unroll
      for (int hh = 0; hh < 8; ++hh)
        x[hh] = *(const unsigned int*)&EA[p][hh][s_sm][tp * 2];
      // low t
      {
        float pe[8]; float sum = 0.f;
#pragma unroll
        for (int hh = 0; hh < 8; ++hh) {
          pe[hh] = exp2f(__half2float(__ushort_as_half((unsigned short)(x[hh] & 0xffffu))));
          sum += pe[hh];
        }
        float inv = __builtin_amdgcn_rcpf(sum);
#pragma unroll
        for (int hh = 0; hh < 8; ++hh) {
          unsigned int u = __float_as_uint(pe[hh] * inv) + 0x8000u;
          EA[p][hh][s_sm][tp * 2] = (unsigned short)(u >> 16);
        }
      }
      // high t
      {
        float pe[8]; float sum = 0.f;
#pragma unroll
        for (int hh = 0; hh < 8; ++hh) {
          pe[hh] = exp2f(__half2float(__ushort_as_half((unsigned short)(x[hh] >> 16))));
          sum += pe[hh];
        }
        float inv = __builtin_amdgcn_rcpf(sum);
#pragma unroll
        for (int hh = 0; hh < 8; ++hh) {
          unsigned int u = __float_as_uint(pe[hh] * inv) + 0x8000u;
          EA[p][hh][s_sm][tp * 2 + 1] = (unsigned short)(u >> 16);
        }
      }
    }
    __syncthreads();
    // ping-pong EA protects next tile's score writes (no 3rd barrier)

    // ---- PV: af from EA (A-layout), vf direct from global bf16 [d][t] ----
    {
      short8 vf[4];
#pragma unroll
      for (int df = 0; df < 4; ++df)
        vf[df] = *(const short8*)(Vth + (size_t)(df * 16 + l15) * S_LEN + t0 + quad * 8);
      short8 af[2];
#pragma unroll
      for (int ss = 0; ss < 2; ++ss)
        af[ss] = *(const short8*)&EA[p][h][ss * 16 + l15][quad * 8];
#pragma unroll
      for (int ss = 0; ss < 2; ++ss)
#pragma unroll
        for (int df = 0; df < 4; ++df)
          acc[ss][df] = __builtin_amdgcn_mfma_f32_16x16x32_bf16(af[ss], vf[df], acc[ss][df], 0, 0, 0);
    }
  }

  // ---- epilogue: partials as packed bf16 s-pairs. layout [tc][b][h][sp][d]
  unsigned int* pb = part + ((size_t)(tc * 2 + b) * NHEAD + h) * (2048ull * 64);
  const int spb = (s0 >> 1) + quad * 2;
#pragma unroll
  for (int ss = 0; ss < 2; ++ss)
#pragma unroll
    for (int df = 0; df < 4; ++df)
#pragma unroll
      for (int rp = 0; rp < 2; ++rp) {
        unsigned int ulo = __float_as_uint(acc[ss][df][rp * 2])     + 0x8000u;
        unsigned int uhi = __float_as_uint(acc[ss][df][rp * 2 + 1]) + 0x8000u;
        unsigned int pk  = __builtin_amdgcn_perm(uhi, ulo, 0x07060302u);
        pb[(size_t)(spb + ss * 8 + rp) * 64 + df * 16 + l15] = pk;
      }
}

// ---------------- reduce: sum 8 tc-partials (packed bf16 pairs) -> fp32 O ----------------
__global__ __launch_bounds__(256)
void reduce_partials(const unsigned int* __restrict__ part, float* __restrict__ out) {
  const size_t TCSTRIDE = 2097152;   // u32 per tc = 2b*8h*2048sp*64d
  size_t i = ((size_t)blockIdx.x * 256 + threadIdx.x) * 4;
  if (i >= TCSTRIDE) return;
  float lo[4] = {0.f, 0.f, 0.f, 0.f}, hi[4] = {0.f, 0.f, 0.f, 0.f};
#pragma unroll
  for (int tc = 0; tc < 8; ++tc) {
    uint4 v = *(const uint4*)(part + tc * TCSTRIDE + i);
    lo[0] += __uint_as_float(v.x << 16); hi[0] += __uint_as_float(v.x & 0xffff0000u);
    lo[1] += __uint_as_float(v.y << 16); hi[1] += __uint_as_float(v.y & 0xffff0000u);
    lo[2] += __uint_as_float(v.z << 16); hi[2] += __uint_as_float(v.z & 0xffff0000u);
    lo[3] += __uint_as_float(v.w << 16); hi[3] += __uint_as_float(v.w & 0xffff0000u);
  }
  size_t bh = i >> 17;                    // 131072 u32 per (b,h)
  unsigned int r = (unsigned int)(i & 131071u);
  unsigned int sp = r >> 6, d = r & 63u;
  float* o = out + ((size_t)bh * S_LEN + 2 * sp) * HEADD + d;
  *(float4v*)o        = (float4v){lo[0], lo[1], lo[2], lo[3]};
  *(float4v*)(o + 64) = (float4v){hi[0], hi[1], hi[2], hi[3]};
}

// ---------------- zero-workspace fallback (round-1 kernel, known correct) ----------------
__global__ __launch_bounds__(512, 2)
void attn_fallback(const float* __restrict__ Qg0, const float* __restrict__ Kg0,
                   const float* __restrict__ Vg0, float* __restrict__ Og0) {
  __shared__ __align__(16) unsigned short Klds[NHEAD][32][72];
  __shared__ __align__(16) unsigned short Vlds[NHEAD][HEADD][40];
  __shared__ __align__(16) unsigned short EA2[NHEAD][64][40];
  const int tid = threadIdx.x, h = tid >> 6, lane = tid & 63, quad = lane >> 4, l15 = lane & 15;
  const int b = blockIdx.x >> 6, s0 = (blockIdx.x & 63) * 64;
  const float* Qg = Qg0 + ((size_t)(b * NHEAD + h)) * S_LEN * HEADD;
  const float* Kg = Kg0 + ((size_t)(b * NHEAD + h)) * HEADD * S_LEN;
  const float* Vg = Vg0 + ((size_t)(b * NHEAD + h)) * S_LEN * HEADD;
  float* Og = Og0 + ((size_t)(b * NHEAD + h)) * S_LEN * HEADD;
  const float SC = 0.04419417382415922f;
  short8 qf[4][2];
#pragma unroll
  for (int ss = 0; ss < 4; ++ss)
#pragma unroll
    for (int kk = 0; kk < 2; ++kk) {
      const float* p = Qg + (size_t)(s0 + ss * 16 + l15) * HEADD + kk * 32 + quad * 8;
      float4v a0 = *(const float4v*)p; float4v a1 = *(const float4v*)(p + 4);
      short8 f;
      f[0] = (short)f2bf(a0[0]); f[1] = (short)f2bf(a0[1]); f[2] = (short)f2bf(a0[2]); f[3] = (short)f2bf(a0[3]);
      f[4] = (short)f2bf(a1[0]); f[5] = (short)f2bf(a1[1]); f[6] = (short)f2bf(a1[2]); f[7] = (short)f2bf(a1[3]);
      qf[ss][kk] = f;
    }
  float4v acc[4][4];
#pragma unroll
  for (int ss = 0; ss < 4; ++ss)
#pragma unroll
    for (int ds = 0; ds < 4; ++ds) acc[ss][ds] = (float4v){0.f, 0.f, 0.f, 0.f};
  const int koct = lane >> 3, kt4 = (lane & 7) * 4, vdq = lane & 15, vtg = lane >> 4;
  const int s_sm = tid >> 3, t4_sm = (tid & 7) * 4;
  for (int it = 0; it < S_LEN / 32; ++it) {
    const int t0 = it * 32;
    {
      float buf[8][4];
#pragma unroll
      for (int j = 0; j < 8; ++j) {
        float4v v = *(const float4v*)(Kg + (size_t)(koct * 8 + j) * S_LEN + t0 + kt4);
        buf[j][0] = v[0]; buf[j][1] = v[1]; buf[j][2] = v[2]; buf[j][3] = v[3];
      }
#pragma unroll
      for (int c = 0; c < 4; ++c) {
        short8 f;
#pragma unroll
        for (int j = 0; j < 8; ++j) f[j] = (short)f2bf(buf[j][c]);
        *(short8*)&Klds[h][kt4 + c][koct * 8] = f;
      }
    }
    {
      float buf[8][4];
#pragma unroll
      for (int j = 0; j < 8; ++j) {
        float4v v = *(const float4v*)(Vg + (size_t)(t0 + vtg * 8 + j) * HEADD + vdq * 4);
        buf[j][0] = v[0]; buf[j][1] = v[1]; buf[j][2] = v[2]; buf[j][3] = v[3];
      }
#pragma unroll
      for (int c = 0; c < 4; ++c) {
        short8 f;
#pragma unroll
        for (int j = 0; j < 8; ++j) f[j] = (short)f2bf(buf[j][c]);
        *(short8*)&Vlds[h][vdq * 4 + c][vtg * 8] = f;
      }
    }
    __syncthreads();
#pragma unroll
    for (int ts = 0; ts < 2; ++ts) {
      short8 kf0 = *(const short8*)&Klds[h][ts * 16 + l15][quad * 8];
      short8 kf1 = *(const short8*)&Klds[h][ts * 16 + l15][32 + quad * 8];
#pragma unroll
      for (int ss = 0; ss < 4; ++ss) {
        float4v e = (float4v){0.f, 0.f, 0.f, 0.f};
        e = __builtin_amdgcn_mfma_f32_16x16x32_bf16(qf[ss][0], kf0, e, 0, 0, 0);
        e = __builtin_amdgcn_mfma_f32_16x16x32_bf16(qf[ss][1], kf1, e, 0, 0, 0);
#pragma unroll
        for (int r = 0; r < 4; ++r)
          EA2[h][ss * 16 + quad * 4 + r][ts * 16 + l15] = __half_as_ushort(__float2half(e[r] * SC));
      }
    }
    __syncthreads();
    {
      float ev[8][4];
#pragma unroll
      for (int hh = 0; hh < 8; ++hh) {
        unsigned long long u = *(const unsigned long long*)&EA2[hh][s_sm][t4_sm];
        ev[hh][0] = __half2float(__ushort_as_half((unsigned short)u));
        ev[hh][1] = __half2float(__ushort_as_half((unsigned short)(u >> 16)));
        ev[hh][2] = __half2float(__ushort_as_half((unsigned short)(u >> 32)));
        ev[hh][3] = __half2float(__ushort_as_half((unsigned short)(u >> 48)));
      }
#pragma unroll
      for (int c = 0; c < 4; ++c) {
        float m = ev[0][c];
#pragma unroll
        for (int hh = 1; hh < 8; ++hh) m = fmaxf(m, ev[hh][c]);
        float sum = 0.f;
#pragma unroll
        for (int hh = 0; hh < 8; ++hh) { float x = __expf(ev[hh][c] - m); ev[hh][c] = x; sum += x; }
        float inv = __builtin_amdgcn_rcpf(sum);
#pragma unroll
        for (int hh = 0; hh < 8; ++hh) ev[hh][c] *= inv;
      }
#pragma unroll
      for (int hh = 0; hh < 8; ++hh) {
        unsigned short u0 = f2bf(ev[hh][0]), u1 = f2bf(ev[hh][1]), u2 = f2bf(ev[hh][2]), u3 = f2bf(ev[hh][3]);
        unsigned long long w = (unsigned long long)u0 | ((unsigned long long)u1 << 16) |
                               ((unsigned long long)u2 << 32) | ((unsigned long long)u3 << 48);
        *(unsigned long long*)&EA2[hh][s_sm][t4_sm] = w;
      }
    }
    __syncthreads();
    {
      short8 af[4], vf[4];
#pragma unroll
      for (int ss = 0; ss < 4; ++ss) af[ss] = *(const short8*)&EA2[h][ss * 16 + l15][quad * 8];
#pragma unroll
      for (int ds = 0; ds < 4; ++ds) vf[ds] = *(const short8*)&Vlds[h][ds * 16 + l15][quad * 8];
#pragma unroll
      for (int ss = 0; ss < 4; ++ss)
#pragma unroll
        for (int ds = 0; ds < 4; ++ds)
          acc[ss][ds] = __builtin_amdgcn_mfma_f32_16x16x32_bf16(af[ss], vf[ds], acc[ss][ds], 0, 0, 0);
    }
    __syncthreads();
  }
#pragma unroll
  for (int ss = 0; ss < 4; ++ss)
#pragma unroll
    for (int ds = 0; ds < 4; ++ds)
#pragma unroll
      for (int r = 0; r < 4; ++r)
        Og[(size_t)(s0 + ss * 16 + quad * 4 + r) * HEADD + ds * 16 + l15] = acc[ss][ds][r];
}

extern "C" void kernel_launch(void* const* d_in, const int* in_sizes, int n_in,
                              void* d_out, int out_size, void* d_ws, size_t ws_size,
                              hipStream_t stream) {
  const float* Q = (const float*)d_in[0];
  const float* K = (const float*)d_in[1];
  const float* V = (const float*)d_in[2];
  float* O = (float*)d_out;

  if (ws_size >= WS_FULL) {
    unsigned short* Kt = (unsigned short*)d_ws;
    unsigned short* Vt = (unsigned short*)((char*)d_ws + VT_OFF);
    unsigned int* part = (unsigned int*)((char*)d_ws + PART_OFF);
    hipLaunchKernelGGL(prepass_cvt, dim3(1024), dim3(256), 0, stream, K, V, Kt, Vt);
    hipLaunchKernelGGL(attn_main, dim3(2048), dim3(512), 0, stream, Q, Kt, Vt, part);
    hipLaunchKernelGGL(reduce_partials, dim3(2048), dim3(256), 0, stream, part, O);
  } else {
    hipLaunchKernelGGL(attn_fallback, dim3(128), dim3(512), 0, stream, Q, K, V, O);
  }
}